// Round 2
// baseline (125.738 us; speedup 1.0000x reference)
//
#include <hip/hip_runtime.h>
#include <math.h>

// QASA layer: out = circuit(x @ W_in.T + b_in, q_weights) @ W_out.T + b_out
// 8 qubits -> 256 complex amps. ONE ROW PER WAVE (8192 waves = full TLP).
// State idx = lane*4 + r: idx bits [7:2] = lane bits [5:0], bits [1:0] = reg.
// Wire i acts on idx bit 7-i.
//
// All 28 CNOTs are eliminated algebraically. The per-layer CNOT ladder
// (0->1,...,6->7) is the GF(2)-linear index map F = I+S (row k = {k,k+1}).
// State is kept in the UN-permuted frame; a gate on bit k after `a` ladders:
//   RX axis mask   = F^a e_k (column action):  a=1:{k,k-1} a=2:{k,k-2}
//                    a=3:{k,k-1,k-2,k-3}
//   RZ sign parity = row_k(F^-a):  F^-1:{k..7}  F^-2:{k,k+2,k+4,k+6}
//                    F^-3:{k,k+1,k+4,k+5}
// Final F^4 absorbed into expvals: row_k(F^-4) = {k,k+4}.
// (Round-1 fix: layer-2 wire-6 RX axis is F e_1 = {bits 1,0} -> reg-mask 3,
//  not 2 — the single wrong mask that caused absmax 0.40.)
//
// Embedding is closed-form: RX(a);RZ(a) on |0> per wire gives a PRODUCT state
// with factors alpha=(c^2,-cs), beta=(s^2,-cs); amplitudes are an 8-factor
// complex product (zero cross-lane) instead of 8 full gates.

__device__ __forceinline__ int f2i(float v) { return __float_as_int(v); }
__device__ __forceinline__ float i2f(int v) { return __int_as_float(v); }

template <int CTRL>
__device__ __forceinline__ float dppf(float v) {
    return i2f(__builtin_amdgcn_update_dpp(0, f2i(v), CTRL, 0xF, 0xF, true));
}

// generalized xor-mask cross-lane: DPP where possible, ds_swizzle <32, shfl >=32
template <int ML>
__device__ __forceinline__ float gshm(float v) {
    static_assert(ML > 0 && ML < 64, "lane mask");
    if constexpr (ML == 1)      return dppf<0xB1>(v);        // quad_perm [1,0,3,2]
    else if constexpr (ML == 2) return dppf<0x4E>(v);        // quad_perm [2,3,0,1]
    else if constexpr (ML == 3) return dppf<0x1B>(v);        // quad_perm [3,2,1,0]
    else if constexpr (ML == 8) return dppf<0x128>(v);       // row_ror:8 == xor8
    else if constexpr (ML < 32) return i2f(__builtin_amdgcn_ds_swizzle(f2i(v), 0x1F | (ML << 10)));
    else                        return __shfl_xor(v, ML, 64);
}

template <int L>
__device__ __forceinline__ float rdlane(float v) {
    return i2f(__builtin_amdgcn_readlane(f2i(v), L));
}

// Generalized gate: RX(th1) about axis (lane-mask ML, reg-mask MR), then
// RZ(th2) with sign = parity(lane & ZL) ^ parity(reg & ZR).
template <int ML, int MR, int ZL, int ZR>
__device__ __forceinline__ void ggate(float re[4], float im[4],
                                      float c1, float s1, float c2, float s2,
                                      int lane) {
    // ---- RX on generalized axis ----
    if constexpr (MR == 0) {
#pragma unroll
        for (int r = 0; r < 4; ++r) {
            float pre = gshm<ML>(re[r]);
            float pim = gshm<ML>(im[r]);
            re[r] = c1 * re[r] + s1 * pim;
            im[r] = c1 * im[r] - s1 * pre;
        }
    } else {
        float nre[4], nim[4];
#pragma unroll
        for (int r = 0; r < 4; ++r) {
            float pre, pim;
            if constexpr (ML != 0) {
                pre = gshm<ML>(re[r ^ MR]);
                pim = gshm<ML>(im[r ^ MR]);
            } else {
                pre = re[r ^ MR];
                pim = im[r ^ MR];
            }
            nre[r] = c1 * re[r] + s1 * pim;
            nim[r] = c1 * im[r] - s1 * pre;
        }
#pragma unroll
        for (int r = 0; r < 4; ++r) { re[r] = nre[r]; im[r] = nim[r]; }
    }
    // ---- RZ with generalized parity sign ----
    float ssb;
    if constexpr (ZL == 0) ssb = -s2;
    else                   ssb = (__popc(lane & ZL) & 1) ? s2 : -s2;
#pragma unroll
    for (int r = 0; r < 4; ++r) {
        float ss = (__builtin_popcount(r & ZR) & 1) ? -ssb : ssb;
        float nr = c2 * re[r] - ss * im[r];
        im[r] = c2 * im[r] + ss * re[r];
        re[r] = nr;
    }
}

__global__ void __launch_bounds__(256, 4) qasa_kernel(
    const float* __restrict__ x, const float* __restrict__ W_in,
    const float* __restrict__ b_in, const float* __restrict__ qw,
    const float* __restrict__ W_out, const float* __restrict__ b_out,
    float* __restrict__ out)
{
    const int tid = threadIdx.x;
    const int lane = tid & 63;
    const size_t row = (size_t)blockIdx.x * 4 + (tid >> 6);

    // per-wave layer trig, lane-indexed in VGPRs (qw has exactly 64 entries)
    float vc, vs;
    __sincosf(0.5f * qw[lane], &vs, &vc);

    // ---- phase 1: angles = x[row] @ W_in.T + b_in ----
    float acc[8] = {0.f, 0.f, 0.f, 0.f, 0.f, 0.f, 0.f, 0.f};
    {
        const float4* xr = (const float4*)(x + row * 1024);
        const float4* w4 = (const float4*)W_in;
#pragma unroll
        for (int k = 0; k < 4; ++k) {
            float4 xv = xr[lane + 64 * k];
#pragma unroll
            for (int q = 0; q < 8; ++q) {
                float4 wv = w4[q * 256 + lane + 64 * k];
                acc[q] += xv.x * wv.x + xv.y * wv.y + xv.z * wv.z + xv.w * wv.w;
            }
        }
    }
    // partial-reduce each acc over lane bits {0,1,3} (DPP only)
#pragma unroll
    for (int q = 0; q < 8; ++q) {
        acc[q] += dppf<0xB1>(acc[q]);
        acc[q] += dppf<0x4E>(acc[q]);
        acc[q] += dppf<0x128>(acc[q]);
    }
    // transpose: lane picks acc[j], j = b0 | b1<<1 | b3<<2
    const int b0 = lane & 1, b1 = (lane >> 1) & 1, b3 = (lane >> 3) & 1;
    float t01 = b0 ? acc[1] : acc[0];
    float t23 = b0 ? acc[3] : acc[2];
    float t45 = b0 ? acc[5] : acc[4];
    float t67 = b0 ? acc[7] : acc[6];
    float ta = b1 ? t23 : t01;
    float tb = b1 ? t67 : t45;
    float A = b3 ? tb : ta;
    // finish: sum over lane bits {2,4,5}
    A += gshm<4>(A); A += gshm<16>(A); A += gshm<32>(A);
    A += b_in[b0 | (b1 << 1) | (b3 << 2)];
    float ec, es;
    __sincosf(0.5f * A, &es, &ec);  // lane L_q holds trig of angle q

    // ---- phase 2a: embedding as product state (zero cross-lane) ----
    // per-wire factors: alpha = (c^2, -cs) for bit 0, beta = (s^2, -cs) for bit 1
    float cc = ec * ec;
    float sq = es * es;
    float ncs = -(ec * es);

    float re[4], im[4];
    float P_re, P_im;
    {   // wire 0 (trig lane 0), bit = lane bit 5
        float Ar = rdlane<0>(cc), Br = rdlane<0>(sq);
        P_re = ((lane >> 5) & 1) ? Br : Ar;
        P_im = rdlane<0>(ncs);
    }
    // trig lane of wire w: L_w = (w&3) | ((w>>2)<<3)
#define PMUL(W_) { \
        constexpr int L_ = ((W_) & 3) | ((((W_) >> 2) & 1) << 3); \
        float Ar = rdlane<L_>(cc), Br = rdlane<L_>(sq), Ai = rdlane<L_>(ncs); \
        float Fr = ((lane >> (5 - (W_))) & 1) ? Br : Ar; \
        float tr = P_re * Fr - P_im * Ai; \
        P_im = P_re * Ai + P_im * Fr; \
        P_re = tr; }
    PMUL(1) PMUL(2) PMUL(3) PMUL(4) PMUL(5)
#undef PMUL
    {   // wires 6 (reg bit1, trig lane 10) and 7 (reg bit0, trig lane 11)
        float A6r = rdlane<10>(cc), B6r = rdlane<10>(sq), A6i = rdlane<10>(ncs);
        float A7r = rdlane<11>(cc), B7r = rdlane<11>(sq), A7i = rdlane<11>(ncs);
#pragma unroll
        for (int r = 0; r < 4; ++r) {
            float g6r = (r & 2) ? B6r : A6r;
            float g7r = (r & 1) ? B7r : A7r;
            float fre = g6r * g7r - A6i * A7i;
            float fim = g6r * A7i + A6i * g7r;
            re[r] = P_re * fre - P_im * fim;
            im[r] = P_re * fim + P_im * fre;
        }
    }

    // ---- phase 2b: variational layers, CNOTs absorbed into gate masks ----
    // qw[l][0][i] -> lane 16l+i (RX), qw[l][1][i] -> lane 16l+8+i (RZ)
#define GG(Lx, W_, ML_, MR_, ZL_, ZR_) \
    ggate<ML_, MR_, ZL_, ZR_>(re, im, \
        rdlane<16 * (Lx) + (W_)>(vc), rdlane<16 * (Lx) + (W_)>(vs), \
        rdlane<16 * (Lx) + 8 + (W_)>(vc), rdlane<16 * (Lx) + 8 + (W_)>(vs), lane);

    // layer 1 (a=0): plain wires
    GG(0,0, 32,0, 32,0)  GG(0,1, 16,0, 16,0)  GG(0,2, 8,0, 8,0)   GG(0,3, 4,0, 4,0)
    GG(0,4, 2,0, 2,0)    GG(0,5, 1,0, 1,0)    GG(0,6, 0,2, 0,2)   GG(0,7, 0,1, 0,1)
    // layer 2 (a=1): axis F e_k = {k,k-1}; RZ rows of F^-1 = {k..7}
    GG(1,0, 48,0, 32,0)  GG(1,1, 24,0, 48,0)  GG(1,2, 12,0, 56,0) GG(1,3, 6,0, 60,0)
    GG(1,4, 3,0, 62,0)   GG(1,5, 1,2, 63,0)   GG(1,6, 0,3, 63,2)  GG(1,7, 0,1, 63,3)
    // layer 3 (a=2): axis {k,k-2}; RZ rows of F^-2 = {k,k+2,k+4,k+6}
    GG(2,0, 40,0, 32,0)  GG(2,1, 20,0, 16,0)  GG(2,2, 10,0, 40,0) GG(2,3, 5,0, 20,0)
    GG(2,4, 2,2, 42,0)   GG(2,5, 1,1, 21,0)   GG(2,6, 0,2, 42,2)  GG(2,7, 0,1, 21,1)
    // layer 4 (a=3): axis {k,k-1,k-2,k-3}; RZ rows of F^-3 = {k,k+1,k+4,k+5}
    GG(3,0, 60,0, 32,0)  GG(3,1, 30,0, 48,0)  GG(3,2, 15,0, 24,0) GG(3,3, 7,2, 12,0)
    GG(3,4, 3,3, 38,0)   GG(3,5, 1,3, 51,0)   GG(3,6, 0,3, 25,2)  GG(3,7, 0,1, 12,3)
#undef GG

    // ---- phase 3: expvals with F^-4-absorbed masks (row_k = {k,k+4}) ----
    //  w0:{b7}->32  w1:{b6}->16  w2:{b5}->8  w3:{b4}->4
    //  w4:{b3,b7}->34  w5:{b2,b6}->17  w6:{b1,b5}->reg2,lane8  w7:{b0,b4}->reg1,lane4
    float p0 = re[0] * re[0] + im[0] * im[0];
    float p1 = re[1] * re[1] + im[1] * im[1];
    float p2 = re[2] * re[2] + im[2] * im[2];
    float p3 = re[3] * re[3] + im[3] * im[3];
    float q0 = (p0 + p1) + (p2 + p3);
    float q2 = (p0 + p1) - (p2 + p3);   // reg-mask 2 (sign by r1)
    float q1 = (p0 + p2) - (p1 + p3);   // reg-mask 1 (sign by r0)

    // full signed Walsh butterfly on q0: lane mu ends with coeff(mask=mu)
    float v = q0;
    { float u = dppf<0xB1>(v);  v = (lane & 1)  ? (u - v) : (v + u); }
    { float u = dppf<0x4E>(v);  v = (lane & 2)  ? (u - v) : (v + u); }
    { float u = dppf<0x128>(v); v = (lane & 8)  ? (u - v) : (v + u); }
    { float u = gshm<4>(v);     v = (lane & 4)  ? (u - v) : (v + u); }
    { float u = gshm<16>(v);    v = (lane & 16) ? (u - v) : (v + u); }
    { float u = gshm<32>(v);    v = (lane & 32) ? (u - v) : (v + u); }
    const float EV0 = rdlane<32>(v), EV1 = rdlane<16>(v), EV2 = rdlane<8>(v);
    const float EV3 = rdlane<4>(v),  EV4 = rdlane<34>(v), EV5 = rdlane<17>(v);

    // q2: need coeff at lane-mask 8 (signed step at bit3 only)
    q2 += dppf<0xB1>(q2);
    q2 += dppf<0x4E>(q2);
    { float u = dppf<0x128>(q2); q2 = (lane & 8) ? (u - q2) : (q2 + u); }
    q2 += gshm<4>(q2); q2 += gshm<16>(q2); q2 += gshm<32>(q2);
    const float EV6 = rdlane<8>(q2);

    // q1: need coeff at lane-mask 4 (signed step at bit2 only)
    q1 += dppf<0xB1>(q1);
    q1 += dppf<0x4E>(q1);
    q1 += dppf<0x128>(q1);
    { float u = gshm<4>(q1); q1 = (lane & 4) ? (u - q1) : (q1 + u); }
    q1 += gshm<16>(q1); q1 += gshm<32>(q1);
    const float EV7 = rdlane<4>(q1);

    // ---- phase 4: out[row] = ev @ W_out.T + b_out (float4 cols per lane) ----
    const float4* wo = (const float4*)W_out;
    const float4* bo = (const float4*)b_out;
    float4* orow = (float4*)(out + row * 1024);
#pragma unroll
    for (int jj = 0; jj < 4; ++jj) {
        const int c4 = lane + 64 * jj;      // float4-col index; col0 = 4*c4
        float4 bias = bo[c4];
        float res[4];
#pragma unroll
        for (int c = 0; c < 4; ++c) {
            float4 wa = wo[2 * (4 * c4 + c)];
            float4 wb = wo[2 * (4 * c4 + c) + 1];
            res[c] = wa.x * EV0 + wa.y * EV1 + wa.z * EV2 + wa.w * EV3
                   + wb.x * EV4 + wb.y * EV5 + wb.z * EV6 + wb.w * EV7;
        }
        float4 o;
        o.x = bias.x + res[0]; o.y = bias.y + res[1];
        o.z = bias.z + res[2]; o.w = bias.w + res[3];
        orow[c4] = o;
    }
}

extern "C" void kernel_launch(void* const* d_in, const int* in_sizes, int n_in,
                              void* d_out, int out_size, void* d_ws, size_t ws_size,
                              hipStream_t stream) {
    const float* x     = (const float*)d_in[0];
    const float* W_in  = (const float*)d_in[1];
    const float* b_in  = (const float*)d_in[2];
    const float* qw    = (const float*)d_in[3];
    const float* W_out = (const float*)d_in[4];
    const float* b_out = (const float*)d_in[5];
    float* outp = (float*)d_out;

    const int B = in_sizes[0] / 1024;   // 8192 rows
    const int grid = B / 4;             // 4 rows (waves) per 256-thread block
    qasa_kernel<<<grid, 256, 0, stream>>>(x, W_in, b_in, qw, W_out, b_out, outp);
}

// Round 3
// 124.879 us; speedup vs baseline: 1.0069x; 1.0069x over previous
//
#include <hip/hip_runtime.h>
#include <math.h>

// QASA layer: out = circuit(x @ W_in.T + b_in, q_weights) @ W_out.T + b_out
// 8 qubits -> 256 complex amps. ONE ROW PER WAVE (8192 waves = full TLP).
// State idx = lane*4 + r: idx bits [7:2] = lane bits [5:0], bits [1:0] = reg.
// Wire i acts on idx bit 7-i.
//
// Structure (round 3):
//  - All 28 CNOTs eliminated algebraically (ladder F = I+S conjugation; see
//    round-2 header). Layers 1-3 act on generalized axes; measurement masks
//    absorb F^-4.
//  - Layer 0 acts wire-locally BEFORE the first ladder, so it is absorbed
//    into the per-wire product-state factors together with the embedding:
//    factor_w = RZ(qw[0,1,w]) RX(qw[0,0,w]) RZ(a_w) RX(a_w) |0>, a 2-vector
//    computed lane-parallel. Only 24 full-state gates remain.
//  - State held as f32x2 pairs (reA=(r0,r1), reB=(r2,r3), imA, imB) so gate
//    math can compile to packed v_pk_fma_f32; reg-partner selection (MR) is
//    a free .yx swizzle.

typedef float f32x2 __attribute__((ext_vector_type(2)));

__device__ __forceinline__ int f2i(float v) { return __float_as_int(v); }
__device__ __forceinline__ float i2f(int v) { return __int_as_float(v); }

template <int CTRL>
__device__ __forceinline__ float dppf(float v) {
    return i2f(__builtin_amdgcn_update_dpp(0, f2i(v), CTRL, 0xF, 0xF, true));
}

// generalized xor-mask cross-lane: DPP where possible, ds_swizzle <32, shfl >=32
template <int ML>
__device__ __forceinline__ float gshm(float v) {
    static_assert(ML > 0 && ML < 64, "lane mask");
    if constexpr (ML == 1)      return dppf<0xB1>(v);        // quad_perm [1,0,3,2]
    else if constexpr (ML == 2) return dppf<0x4E>(v);        // quad_perm [2,3,0,1]
    else if constexpr (ML == 3) return dppf<0x1B>(v);        // quad_perm [3,2,1,0]
    else if constexpr (ML == 8) return dppf<0x128>(v);       // row_ror:8 == xor8
    else if constexpr (ML < 32) return i2f(__builtin_amdgcn_ds_swizzle(f2i(v), 0x1F | (ML << 10)));
    else                        return __shfl_xor(v, ML, 64);
}

template <int L>
__device__ __forceinline__ float rdlane(float v) {
    return i2f(__builtin_amdgcn_readlane(f2i(v), L));
}

// Generalized gate on packed state: RX(th1) about axis (lane-mask ML,
// reg-mask MR), then RZ(th2) with sign = parity(lane&ZL)^parity(r&ZR).
template <int ML, int MR, int ZL, int ZR>
__device__ __forceinline__ void ggate(f32x2& reA, f32x2& reB, f32x2& imA, f32x2& imB,
                                      float c1, float s1, float c2, float s2,
                                      int lane) {
    // ---- partner fetch: reg-swizzle by MR, then lane-xor by ML ----
    f32x2 sReA, sReB, sImA, sImB;
    if constexpr (MR == 0)      { sReA = reA;    sReB = reB;    sImA = imA;    sImB = imB; }
    else if constexpr (MR == 1) { sReA = reA.yx; sReB = reB.yx; sImA = imA.yx; sImB = imB.yx; }
    else if constexpr (MR == 2) { sReA = reB;    sReB = reA;    sImA = imB;    sImB = imA; }
    else                        { sReA = reB.yx; sReB = reA.yx; sImA = imB.yx; sImB = imA.yx; }
    f32x2 pReA, pReB, pImA, pImB;
    if constexpr (ML != 0) {
        pReA.x = gshm<ML>(sReA.x); pReA.y = gshm<ML>(sReA.y);
        pReB.x = gshm<ML>(sReB.x); pReB.y = gshm<ML>(sReB.y);
        pImA.x = gshm<ML>(sImA.x); pImA.y = gshm<ML>(sImA.y);
        pImB.x = gshm<ML>(sImB.x); pImB.y = gshm<ML>(sImB.y);
    } else { pReA = sReA; pReB = sReB; pImA = sImA; pImB = sImB; }
    // ---- RX ----
    f32x2 nReA = c1 * reA + s1 * pImA;
    f32x2 nReB = c1 * reB + s1 * pImB;
    f32x2 nImA = c1 * imA - s1 * pReA;
    f32x2 nImB = c1 * imB - s1 * pReB;
    // ---- RZ: ss_r = sigma(r) * base, base = parity(lane&ZL) ? s2 : -s2 ----
    float base;
    if constexpr (ZL == 0) base = -s2;
    else                   base = (__popc(lane & ZL) & 1) ? s2 : -s2;
    constexpr bool N1 = (ZR & 1) != 0;                       // sigma(1)
    constexpr bool N2 = ((ZR >> 1) & 1) != 0;                // sigma(2)
    constexpr bool N3 = (((ZR & 1) ^ ((ZR >> 1) & 1)) != 0); // sigma(3)
    f32x2 ssA = { base, N1 ? -base : base };
    f32x2 ssB = { N2 ? -base : base, N3 ? -base : base };
    f32x2 tA = c2 * nReA - ssA * nImA;
    f32x2 tB = c2 * nReB - ssB * nImB;
    imA = c2 * nImA + ssA * nReA;
    imB = c2 * nImB + ssB * nReB;
    reA = tA;
    reB = tB;
}

__global__ void __launch_bounds__(256, 4) qasa_kernel(
    const float* __restrict__ x, const float* __restrict__ W_in,
    const float* __restrict__ b_in, const float* __restrict__ qw,
    const float* __restrict__ W_out, const float* __restrict__ b_out,
    float* __restrict__ out)
{
    const int tid = threadIdx.x;
    const int lane = tid & 63;
    const size_t row = (size_t)blockIdx.x * 4 + (tid >> 6);

    // per-wave layer trig, lane-indexed in VGPRs (qw has exactly 64 entries)
    float vc, vs;
    __sincosf(0.5f * qw[lane], &vs, &vc);

    // ---- phase 1: angles = x[row] @ W_in.T + b_in ----
    float acc[8] = {0.f, 0.f, 0.f, 0.f, 0.f, 0.f, 0.f, 0.f};
    {
        const float4* xr = (const float4*)(x + row * 1024);
        const float4* w4 = (const float4*)W_in;
#pragma unroll
        for (int k = 0; k < 4; ++k) {
            float4 xv = xr[lane + 64 * k];
#pragma unroll
            for (int q = 0; q < 8; ++q) {
                float4 wv = w4[q * 256 + lane + 64 * k];
                acc[q] += xv.x * wv.x + xv.y * wv.y + xv.z * wv.z + xv.w * wv.w;
            }
        }
    }
    // partial-reduce each acc over lane bits {0,1,3} (DPP only)
#pragma unroll
    for (int q = 0; q < 8; ++q) {
        acc[q] += dppf<0xB1>(acc[q]);
        acc[q] += dppf<0x4E>(acc[q]);
        acc[q] += dppf<0x128>(acc[q]);
    }
    // transpose: lane picks acc[j], j = b0 | b1<<1 | b3<<2
    const int b0 = lane & 1, b1 = (lane >> 1) & 1, b3 = (lane >> 3) & 1;
    float t01 = b0 ? acc[1] : acc[0];
    float t23 = b0 ? acc[3] : acc[2];
    float t45 = b0 ? acc[5] : acc[4];
    float t67 = b0 ? acc[7] : acc[6];
    float ta = b1 ? t23 : t01;
    float tb = b1 ? t67 : t45;
    float A = b3 ? tb : ta;
    // finish: sum over lane bits {2,4,5}
    A += gshm<4>(A); A += gshm<16>(A); A += gshm<32>(A);
    A += b_in[b0 | (b1 << 1) | (b3 << 2)];
    float ca, sa;
    __sincosf(0.5f * A, &sa, &ca);  // lane L_q holds trig of angle q

    // ---- phase 2a: per-wire factor = RZ(qz) RX(qx) RZ(a) RX(a) |0> ----
    // embedding part: u = (ca^2, -ca*sa), v = (sa^2, -ca*sa)
    float ur = ca * ca, ui = -ca * sa, vr = sa * sa, vi = ui;
    // layer-0 weights gathered per lane for qubit q(lane) = b0|b1<<1|b3<<2
    const int q = b0 | (b1 << 1) | (b3 << 2);
    const int a1 = 4 * q, a2 = 4 * (q + 8);
    float cx = i2f(__builtin_amdgcn_ds_bpermute(a1, f2i(vc)));
    float sx = i2f(__builtin_amdgcn_ds_bpermute(a1, f2i(vs)));
    float cz = i2f(__builtin_amdgcn_ds_bpermute(a2, f2i(vc)));
    float sz = i2f(__builtin_amdgcn_ds_bpermute(a2, f2i(vs)));
    // RX(qx): u' = cx*u - i sx*v ; v' = cx*v - i sx*u
    float ur1 = cx * ur + sx * vi, ui1 = cx * ui - sx * vr;
    float vr1 = cx * vr + sx * ui, vi1 = cx * vi - sx * ur;
    // RZ(qz): u'' = (cz - i sz) u' ; v'' = (cz + i sz) v'
    float ur2 = cz * ur1 + sz * ui1, ui2 = cz * ui1 - sz * ur1;
    float vr2 = cz * vr1 - sz * vi1, vi2 = cz * vi1 + sz * vr1;
    // factor for qubit w lives in lane RL_w = {0,1,2,3,8,9,10,11}

    // ---- phase 2b-init: product expansion (state after layer 0) ----
    float Pr, Pi;
    {   // wire 0 (lane bit 5), factor in lane 0
        float fur = rdlane<0>(ur2), fui = rdlane<0>(ui2);
        float fvr = rdlane<0>(vr2), fvi = rdlane<0>(vi2);
        bool b = (lane >> 5) & 1;
        Pr = b ? fvr : fur;
        Pi = b ? fvi : fui;
    }
#define PMUL(W_, L_) { \
        float fur = rdlane<L_>(ur2), fui = rdlane<L_>(ui2); \
        float fvr = rdlane<L_>(vr2), fvi = rdlane<L_>(vi2); \
        bool b = (lane >> (5 - (W_))) & 1; \
        float fr = b ? fvr : fur, fi = b ? fvi : fui; \
        float tr = Pr * fr - Pi * fi; \
        Pi = Pr * fi + Pi * fr; \
        Pr = tr; }
    PMUL(1, 1) PMUL(2, 2) PMUL(3, 3) PMUL(4, 8) PMUL(5, 9)
#undef PMUL
    f32x2 reA, reB, imA, imB;
    {   // wires 6 (reg bit1, lane 10) and 7 (reg bit0, lane 11)
        float u6r = rdlane<10>(ur2), u6i = rdlane<10>(ui2);
        float v6r = rdlane<10>(vr2), v6i = rdlane<10>(vi2);
        float u7r = rdlane<11>(ur2), u7i = rdlane<11>(ui2);
        float v7r = rdlane<11>(vr2), v7i = rdlane<11>(vi2);
        float rr[4], ii[4];
#pragma unroll
        for (int r = 0; r < 4; ++r) {
            float g6r_ = (r & 2) ? v6r : u6r, g6i_ = (r & 2) ? v6i : u6i;
            float g7r_ = (r & 1) ? v7r : u7r, g7i_ = (r & 1) ? v7i : u7i;
            float fr = g6r_ * g7r_ - g6i_ * g7i_;
            float fi = g6r_ * g7i_ + g6i_ * g7r_;
            rr[r] = Pr * fr - Pi * fi;
            ii[r] = Pr * fi + Pi * fr;
        }
        reA = (f32x2){ rr[0], rr[1] };  reB = (f32x2){ rr[2], rr[3] };
        imA = (f32x2){ ii[0], ii[1] };  imB = (f32x2){ ii[2], ii[3] };
    }

    // ---- phase 2b: layers 1-3, CNOTs absorbed into gate masks ----
    // qw[l][0][i] -> lane 16l+i (RX), qw[l][1][i] -> lane 16l+8+i (RZ)
#define GG(Lx, W_, ML_, MR_, ZL_, ZR_) \
    ggate<ML_, MR_, ZL_, ZR_>(reA, reB, imA, imB, \
        rdlane<16 * (Lx) + (W_)>(vc), rdlane<16 * (Lx) + (W_)>(vs), \
        rdlane<16 * (Lx) + 8 + (W_)>(vc), rdlane<16 * (Lx) + 8 + (W_)>(vs), lane);

    // layer 2 (a=1): axis F e_k = {k,k-1}; RZ rows of F^-1 = {k..7}
    GG(1,0, 48,0, 32,0)  GG(1,1, 24,0, 48,0)  GG(1,2, 12,0, 56,0) GG(1,3, 6,0, 60,0)
    GG(1,4, 3,0, 62,0)   GG(1,5, 1,2, 63,0)   GG(1,6, 0,3, 63,2)  GG(1,7, 0,1, 63,3)
    // layer 3 (a=2): axis {k,k-2}; RZ rows of F^-2 = {k,k+2,k+4,k+6}
    GG(2,0, 40,0, 32,0)  GG(2,1, 20,0, 16,0)  GG(2,2, 10,0, 40,0) GG(2,3, 5,0, 20,0)
    GG(2,4, 2,2, 42,0)   GG(2,5, 1,1, 21,0)   GG(2,6, 0,2, 42,2)  GG(2,7, 0,1, 21,1)
    // layer 4 (a=3): axis {k,k-1,k-2,k-3}; RZ rows of F^-3 = {k,k+1,k+4,k+5}
    GG(3,0, 60,0, 32,0)  GG(3,1, 30,0, 48,0)  GG(3,2, 15,0, 24,0) GG(3,3, 7,2, 12,0)
    GG(3,4, 3,3, 38,0)   GG(3,5, 1,3, 51,0)   GG(3,6, 0,3, 25,2)  GG(3,7, 0,1, 12,3)
#undef GG

    // ---- phase 3: expvals with F^-4-absorbed masks (row_k = {k,k+4}) ----
    //  w0:{b7}->32  w1:{b6}->16  w2:{b5}->8  w3:{b4}->4
    //  w4:{b3,b7}->34  w5:{b2,b6}->17  w6:{b1,b5}->reg2,lane8  w7:{b0,b4}->reg1,lane4
    float p0 = reA.x * reA.x + imA.x * imA.x;
    float p1 = reA.y * reA.y + imA.y * imA.y;
    float p2 = reB.x * reB.x + imB.x * imB.x;
    float p3 = reB.y * reB.y + imB.y * imB.y;
    float q0 = (p0 + p1) + (p2 + p3);
    float q2 = (p0 + p1) - (p2 + p3);   // reg-mask 2 (sign by r1)
    float q1 = (p0 + p2) - (p1 + p3);   // reg-mask 1 (sign by r0)

    // full signed Walsh butterfly on q0: lane mu ends with coeff(mask=mu)
    float v = q0;
    { float u = dppf<0xB1>(v);  v = (lane & 1)  ? (u - v) : (v + u); }
    { float u = dppf<0x4E>(v);  v = (lane & 2)  ? (u - v) : (v + u); }
    { float u = dppf<0x128>(v); v = (lane & 8)  ? (u - v) : (v + u); }
    { float u = gshm<4>(v);     v = (lane & 4)  ? (u - v) : (v + u); }
    { float u = gshm<16>(v);    v = (lane & 16) ? (u - v) : (v + u); }
    { float u = gshm<32>(v);    v = (lane & 32) ? (u - v) : (v + u); }
    const float EV0 = rdlane<32>(v), EV1 = rdlane<16>(v), EV2 = rdlane<8>(v);
    const float EV3 = rdlane<4>(v),  EV4 = rdlane<34>(v), EV5 = rdlane<17>(v);

    // q2: need coeff at lane-mask 8 (signed step at bit3 only)
    q2 += dppf<0xB1>(q2);
    q2 += dppf<0x4E>(q2);
    { float u = dppf<0x128>(q2); q2 = (lane & 8) ? (u - q2) : (q2 + u); }
    q2 += gshm<4>(q2); q2 += gshm<16>(q2); q2 += gshm<32>(q2);
    const float EV6 = rdlane<8>(q2);

    // q1: need coeff at lane-mask 4 (signed step at bit2 only)
    q1 += dppf<0xB1>(q1);
    q1 += dppf<0x4E>(q1);
    q1 += dppf<0x128>(q1);
    { float u = gshm<4>(q1); q1 = (lane & 4) ? (u - q1) : (q1 + u); }
    q1 += gshm<16>(q1); q1 += gshm<32>(q1);
    const float EV7 = rdlane<4>(q1);

    // ---- phase 4: out[row] = ev @ W_out.T + b_out (packed dot products) ----
    const f32x2 E01 = { EV0, EV1 }, E23 = { EV2, EV3 };
    const f32x2 E45 = { EV4, EV5 }, E67 = { EV6, EV7 };
    const float4* wo = (const float4*)W_out;
    const float4* bo = (const float4*)b_out;
    float4* orow = (float4*)(out + row * 1024);
#pragma unroll
    for (int jj = 0; jj < 4; ++jj) {
        const int c4 = lane + 64 * jj;      // float4-col index; col0 = 4*c4
        float4 bias = bo[c4];
        float res[4];
#pragma unroll
        for (int c = 0; c < 4; ++c) {
            float4 wa = wo[2 * (4 * c4 + c)];
            float4 wb = wo[2 * (4 * c4 + c) + 1];
            f32x2 acc2 = E01 * (f32x2){ wa.x, wa.y } + E23 * (f32x2){ wa.z, wa.w }
                       + E45 * (f32x2){ wb.x, wb.y } + E67 * (f32x2){ wb.z, wb.w };
            res[c] = acc2.x + acc2.y;
        }
        float4 o;
        o.x = bias.x + res[0]; o.y = bias.y + res[1];
        o.z = bias.z + res[2]; o.w = bias.w + res[3];
        orow[c4] = o;
    }
}

extern "C" void kernel_launch(void* const* d_in, const int* in_sizes, int n_in,
                              void* d_out, int out_size, void* d_ws, size_t ws_size,
                              hipStream_t stream) {
    const float* x     = (const float*)d_in[0];
    const float* W_in  = (const float*)d_in[1];
    const float* b_in  = (const float*)d_in[2];
    const float* qw    = (const float*)d_in[3];
    const float* W_out = (const float*)d_in[4];
    const float* b_out = (const float*)d_in[5];
    float* outp = (float*)d_out;

    const int B = in_sizes[0] / 1024;   // 8192 rows
    const int grid = B / 4;             // 4 rows (waves) per 256-thread block
    qasa_kernel<<<grid, 256, 0, stream>>>(x, W_in, b_in, qw, W_out, b_out, outp);
}

// Round 4
// 105.117 us; speedup vs baseline: 1.1962x; 1.1880x over previous
//
#include <hip/hip_runtime.h>
#include <math.h>

// QASA layer: out = circuit(x @ W_in.T + b_in, q_weights) @ W_out.T + b_out
// 8 qubits -> 256 complex amps. ONE ROW PER WAVE (8192 waves = full TLP).
// State idx = lane*4 + r: idx bits [7:2] = lane bits [5:0], bits [1:0] = reg.
// Wire i acts on idx bit 7-i.
//
// Round 4: block-cooperative GEMV phases. Waves in a block share W_in/W_out
// reads (weights fetched once per BLOCK, not per wave): phase 1 splits the
// 8 q-rows across 4 waves (each computes 2 q x 4 rows over full K), phase 4
// splits the 1024 output cols (each wave owns 256 cols x 4 rows). Angles and
// EVs exchanged through 256 B of LDS. Cuts per-wave load traffic 72->21 KB.
//
// Circuit (unchanged from round 3): CNOT ladders eliminated by F=I+S
// conjugation; layer 0 + embedding absorbed into per-wire product factors;
// state packed as f32x2 for v_pk_fma_f32.

typedef float f32x2 __attribute__((ext_vector_type(2)));

__device__ __forceinline__ int f2i(float v) { return __float_as_int(v); }
__device__ __forceinline__ float i2f(int v) { return __int_as_float(v); }

template <int CTRL>
__device__ __forceinline__ float dppf(float v) {
    return i2f(__builtin_amdgcn_update_dpp(0, f2i(v), CTRL, 0xF, 0xF, true));
}

// generalized xor-mask cross-lane: DPP where possible, ds_swizzle <32, shfl >=32
template <int ML>
__device__ __forceinline__ float gshm(float v) {
    static_assert(ML > 0 && ML < 64, "lane mask");
    if constexpr (ML == 1)      return dppf<0xB1>(v);        // quad_perm [1,0,3,2]
    else if constexpr (ML == 2) return dppf<0x4E>(v);        // quad_perm [2,3,0,1]
    else if constexpr (ML == 3) return dppf<0x1B>(v);        // quad_perm [3,2,1,0]
    else if constexpr (ML == 8) return dppf<0x128>(v);       // row_ror:8 == xor8 in 16
    else if constexpr (ML < 32) return i2f(__builtin_amdgcn_ds_swizzle(f2i(v), 0x1F | (ML << 10)));
    else                        return __shfl_xor(v, ML, 64);
}

template <int L>
__device__ __forceinline__ float rdlane(float v) {
    return i2f(__builtin_amdgcn_readlane(f2i(v), L));
}

// Generalized gate on packed state: RX(th1) about axis (lane-mask ML,
// reg-mask MR), then RZ(th2) with sign = parity(lane&ZL)^parity(r&ZR).
template <int ML, int MR, int ZL, int ZR>
__device__ __forceinline__ void ggate(f32x2& reA, f32x2& reB, f32x2& imA, f32x2& imB,
                                      float c1, float s1, float c2, float s2,
                                      int lane) {
    // ---- partner fetch: reg-swizzle by MR, then lane-xor by ML ----
    f32x2 sReA, sReB, sImA, sImB;
    if constexpr (MR == 0)      { sReA = reA;    sReB = reB;    sImA = imA;    sImB = imB; }
    else if constexpr (MR == 1) { sReA = reA.yx; sReB = reB.yx; sImA = imA.yx; sImB = imB.yx; }
    else if constexpr (MR == 2) { sReA = reB;    sReB = reA;    sImA = imB;    sImB = imA; }
    else                        { sReA = reB.yx; sReB = reA.yx; sImA = imB.yx; sImB = imA.yx; }
    f32x2 pReA, pReB, pImA, pImB;
    if constexpr (ML != 0) {
        pReA.x = gshm<ML>(sReA.x); pReA.y = gshm<ML>(sReA.y);
        pReB.x = gshm<ML>(sReB.x); pReB.y = gshm<ML>(sReB.y);
        pImA.x = gshm<ML>(sImA.x); pImA.y = gshm<ML>(sImA.y);
        pImB.x = gshm<ML>(sImB.x); pImB.y = gshm<ML>(sImB.y);
    } else { pReA = sReA; pReB = sReB; pImA = sImA; pImB = sImB; }
    // ---- RX ----
    f32x2 nReA = c1 * reA + s1 * pImA;
    f32x2 nReB = c1 * reB + s1 * pImB;
    f32x2 nImA = c1 * imA - s1 * pReA;
    f32x2 nImB = c1 * imB - s1 * pReB;
    // ---- RZ: ss_r = sigma(r) * base, base = parity(lane&ZL) ? s2 : -s2 ----
    float base;
    if constexpr (ZL == 0) base = -s2;
    else                   base = (__popc(lane & ZL) & 1) ? s2 : -s2;
    constexpr bool N1 = (ZR & 1) != 0;                       // sigma(1)
    constexpr bool N2 = ((ZR >> 1) & 1) != 0;                // sigma(2)
    constexpr bool N3 = (((ZR & 1) ^ ((ZR >> 1) & 1)) != 0); // sigma(3)
    f32x2 ssA = { base, N1 ? -base : base };
    f32x2 ssB = { N2 ? -base : base, N3 ? -base : base };
    f32x2 tA = c2 * nReA - ssA * nImA;
    f32x2 tB = c2 * nReB - ssB * nImB;
    imA = c2 * nImA + ssA * nReA;
    imB = c2 * nImB + ssB * nReB;
    reA = tA;
    reB = tB;
}

__global__ void __launch_bounds__(256, 4) qasa_kernel(
    const float* __restrict__ x, const float* __restrict__ W_in,
    const float* __restrict__ b_in, const float* __restrict__ qw,
    const float* __restrict__ W_out, const float* __restrict__ b_out,
    float* __restrict__ out)
{
    const int tid = threadIdx.x;
    const int lane = tid & 63;
    const int w = tid >> 6;                       // wave id in block (= row id)
    const int block4 = blockIdx.x * 4;
    const size_t row = (size_t)block4 + w;

    __shared__ float ang[32];                     // [q][r]
    __shared__ float evs[4][8] __attribute__((aligned(16)));  // [r][ev]

    // per-wave layer trig, lane-indexed in VGPRs (qw has exactly 64 entries)
    float vc, vs;
    __sincosf(0.5f * qw[lane], &vs, &vc);

    // ---- phase 1 (cooperative): wave w computes angles[r][q] for q=2w,2w+1,
    //      all 4 rows, over full K. W_in slice read once per block-wave.
    float acc[8] = {0.f, 0.f, 0.f, 0.f, 0.f, 0.f, 0.f, 0.f};  // [qp*4 + r]
    {
        const float4* w4 = (const float4*)W_in;
        const float4* xr0 = (const float4*)(x + (size_t)block4 * 1024);
#pragma unroll
        for (int k = 0; k < 4; ++k) {
            float4 wv0 = w4[(2 * w) * 256 + lane + 64 * k];
            float4 wv1 = w4[(2 * w + 1) * 256 + lane + 64 * k];
#pragma unroll
            for (int r = 0; r < 4; ++r) {
                float4 xv = xr0[r * 256 + lane + 64 * k];
                acc[r]     += xv.x * wv0.x + xv.y * wv0.y + xv.z * wv0.z + xv.w * wv0.w;
                acc[4 + r] += xv.x * wv1.x + xv.y * wv1.y + xv.z * wv1.z + xv.w * wv1.w;
            }
        }
    }
    // partial-reduce each acc over lane bits {0,1,3} (DPP only)
#pragma unroll
    for (int j = 0; j < 8; ++j) {
        acc[j] += dppf<0xB1>(acc[j]);
        acc[j] += dppf<0x4E>(acc[j]);
        acc[j] += dppf<0x128>(acc[j]);
    }
    // transpose: lane picks acc[j], j = b0 | b1<<1 | b3<<2
    const int b0 = lane & 1, b1 = (lane >> 1) & 1, b3 = (lane >> 3) & 1;
    {
        float t01 = b0 ? acc[1] : acc[0];
        float t23 = b0 ? acc[3] : acc[2];
        float t45 = b0 ? acc[5] : acc[4];
        float t67 = b0 ? acc[7] : acc[6];
        float ta = b1 ? t23 : t01;
        float tb = b1 ? t67 : t45;
        float S = b3 ? tb : ta;
        // finish: sum over lane bits {2,4,5} -> every lane has full sum of its j
        S += gshm<4>(S); S += gshm<16>(S); S += gshm<32>(S);
        // writer lanes {0,1,2,3,8,9,10,11}: j = (lane&3) | b3<<2
        if ((lane & 52) == 0) {
            int r = lane & 3, qp = (lane >> 3) & 1;
            ang[(2 * w + qp) * 4 + r] = S;
        }
    }
    __syncthreads();
    const int qofl = b0 | (b1 << 1) | (b3 << 2);  // qubit index held by this lane
    float A = ang[qofl * 4 + w] + b_in[qofl];
    float ca, sa;
    __sincosf(0.5f * A, &sa, &ca);  // lane L_q holds trig of angle q

    // ---- phase 2a: per-wire factor = RZ(qz) RX(qx) RZ(a) RX(a) |0> ----
    // embedding part: u = (ca^2, -ca*sa), v = (sa^2, -ca*sa)
    float ur = ca * ca, ui = -ca * sa, vr = sa * sa, vi = ui;
    const int a1 = 4 * qofl, a2 = 4 * (qofl + 8);
    float cx = i2f(__builtin_amdgcn_ds_bpermute(a1, f2i(vc)));
    float sx = i2f(__builtin_amdgcn_ds_bpermute(a1, f2i(vs)));
    float cz = i2f(__builtin_amdgcn_ds_bpermute(a2, f2i(vc)));
    float sz = i2f(__builtin_amdgcn_ds_bpermute(a2, f2i(vs)));
    // RX(qx): u' = cx*u - i sx*v ; v' = cx*v - i sx*u
    float ur1 = cx * ur + sx * vi, ui1 = cx * ui - sx * vr;
    float vr1 = cx * vr + sx * ui, vi1 = cx * vi - sx * ur;
    // RZ(qz): u'' = (cz - i sz) u' ; v'' = (cz + i sz) v'
    float ur2 = cz * ur1 + sz * ui1, ui2 = cz * ui1 - sz * ur1;
    float vr2 = cz * vr1 - sz * vi1, vi2 = cz * vi1 + sz * vr1;
    // factor for qubit q lives in lane {0,1,2,3,8,9,10,11}

    // ---- phase 2b-init: product expansion (state after layer 0) ----
    float Pr, Pi;
    {   // wire 0 (lane bit 5), factor in lane 0
        float fur = rdlane<0>(ur2), fui = rdlane<0>(ui2);
        float fvr = rdlane<0>(vr2), fvi = rdlane<0>(vi2);
        bool b = (lane >> 5) & 1;
        Pr = b ? fvr : fur;
        Pi = b ? fvi : fui;
    }
#define PMUL(W_, L_) { \
        float fur = rdlane<L_>(ur2), fui = rdlane<L_>(ui2); \
        float fvr = rdlane<L_>(vr2), fvi = rdlane<L_>(vi2); \
        bool b = (lane >> (5 - (W_))) & 1; \
        float fr = b ? fvr : fur, fi = b ? fvi : fui; \
        float tr = Pr * fr - Pi * fi; \
        Pi = Pr * fi + Pi * fr; \
        Pr = tr; }
    PMUL(1, 1) PMUL(2, 2) PMUL(3, 3) PMUL(4, 8) PMUL(5, 9)
#undef PMUL
    f32x2 reA, reB, imA, imB;
    {   // wires 6 (reg bit1, lane 10) and 7 (reg bit0, lane 11)
        float u6r = rdlane<10>(ur2), u6i = rdlane<10>(ui2);
        float v6r = rdlane<10>(vr2), v6i = rdlane<10>(vi2);
        float u7r = rdlane<11>(ur2), u7i = rdlane<11>(ui2);
        float v7r = rdlane<11>(vr2), v7i = rdlane<11>(vi2);
        float rr[4], ii[4];
#pragma unroll
        for (int r = 0; r < 4; ++r) {
            float g6r_ = (r & 2) ? v6r : u6r, g6i_ = (r & 2) ? v6i : u6i;
            float g7r_ = (r & 1) ? v7r : u7r, g7i_ = (r & 1) ? v7i : u7i;
            float fr = g6r_ * g7r_ - g6i_ * g7i_;
            float fi = g6r_ * g7i_ + g6i_ * g7r_;
            rr[r] = Pr * fr - Pi * fi;
            ii[r] = Pr * fi + Pi * fr;
        }
        reA = (f32x2){ rr[0], rr[1] };  reB = (f32x2){ rr[2], rr[3] };
        imA = (f32x2){ ii[0], ii[1] };  imB = (f32x2){ ii[2], ii[3] };
    }

    // ---- phase 2b: layers 1-3, CNOTs absorbed into gate masks ----
    // qw[l][0][i] -> lane 16l+i (RX), qw[l][1][i] -> lane 16l+8+i (RZ)
#define GG(Lx, W_, ML_, MR_, ZL_, ZR_) \
    ggate<ML_, MR_, ZL_, ZR_>(reA, reB, imA, imB, \
        rdlane<16 * (Lx) + (W_)>(vc), rdlane<16 * (Lx) + (W_)>(vs), \
        rdlane<16 * (Lx) + 8 + (W_)>(vc), rdlane<16 * (Lx) + 8 + (W_)>(vs), lane);

    // layer 2 (a=1): axis F e_k = {k,k-1}; RZ rows of F^-1 = {k..7}
    GG(1,0, 48,0, 32,0)  GG(1,1, 24,0, 48,0)  GG(1,2, 12,0, 56,0) GG(1,3, 6,0, 60,0)
    GG(1,4, 3,0, 62,0)   GG(1,5, 1,2, 63,0)   GG(1,6, 0,3, 63,2)  GG(1,7, 0,1, 63,3)
    // layer 3 (a=2): axis {k,k-2}; RZ rows of F^-2 = {k,k+2,k+4,k+6}
    GG(2,0, 40,0, 32,0)  GG(2,1, 20,0, 16,0)  GG(2,2, 10,0, 40,0) GG(2,3, 5,0, 20,0)
    GG(2,4, 2,2, 42,0)   GG(2,5, 1,1, 21,0)   GG(2,6, 0,2, 42,2)  GG(2,7, 0,1, 21,1)
    // layer 4 (a=3): axis {k,k-1,k-2,k-3}; RZ rows of F^-3 = {k,k+1,k+4,k+5}
    GG(3,0, 60,0, 32,0)  GG(3,1, 30,0, 48,0)  GG(3,2, 15,0, 24,0) GG(3,3, 7,2, 12,0)
    GG(3,4, 3,3, 38,0)   GG(3,5, 1,3, 51,0)   GG(3,6, 0,3, 25,2)  GG(3,7, 0,1, 12,3)
#undef GG

    // ---- phase 3: expvals with F^-4-absorbed masks (row_k = {k,k+4}) ----
    //  EV0..EV5 from q0-butterfly at lanes {32,16,8,4,34,17};
    //  EV6 = q2 coeff (signed@bit3) at lane 8; EV7 = q1 coeff (signed@bit2) at lane 4.
    float p0 = reA.x * reA.x + imA.x * imA.x;
    float p1 = reA.y * reA.y + imA.y * imA.y;
    float p2 = reB.x * reB.x + imB.x * imB.x;
    float p3 = reB.y * reB.y + imB.y * imB.y;
    float q0 = (p0 + p1) + (p2 + p3);
    float q2 = (p0 + p1) - (p2 + p3);   // reg-mask 2 (sign by r1)
    float q1 = (p0 + p2) - (p1 + p3);   // reg-mask 1 (sign by r0)

    // full signed Walsh butterfly on q0: lane mu ends with coeff(mask=mu)
    float v = q0;
    { float u = dppf<0xB1>(v);  v = (lane & 1)  ? (u - v) : (v + u); }
    { float u = dppf<0x4E>(v);  v = (lane & 2)  ? (u - v) : (v + u); }
    { float u = dppf<0x128>(v); v = (lane & 8)  ? (u - v) : (v + u); }
    { float u = gshm<4>(v);     v = (lane & 4)  ? (u - v) : (v + u); }
    { float u = gshm<16>(v);    v = (lane & 16) ? (u - v) : (v + u); }
    { float u = gshm<32>(v);    v = (lane & 32) ? (u - v) : (v + u); }

    // q2: coeff at lane-mask 8 (signed step at bit3 only)
    q2 += dppf<0xB1>(q2);
    q2 += dppf<0x4E>(q2);
    { float u = dppf<0x128>(q2); q2 = (lane & 8) ? (u - q2) : (q2 + u); }
    q2 += gshm<4>(q2); q2 += gshm<16>(q2); q2 += gshm<32>(q2);

    // q1: coeff at lane-mask 4 (signed step at bit2 only)
    q1 += dppf<0xB1>(q1);
    q1 += dppf<0x4E>(q1);
    q1 += dppf<0x128>(q1);
    { float u = gshm<4>(q1); q1 = (lane & 4) ? (u - q1) : (q1 + u); }
    q1 += gshm<16>(q1); q1 += gshm<32>(q1);

    // write EVs to LDS directly from their holder lanes
    {
        const unsigned long long wrmask = 0x0000000500030110ULL; // lanes 4,8,16,17,32,34
        if ((wrmask >> lane) & 1) {
            int k = 6 - __ffs(lane);        // 32->0,16->1,8->2,4->3,34->4,17->5
            evs[w][k] = v;
        }
        if (lane == 8 || lane == 4) {
            evs[w][(lane == 8) ? 6 : 7] = (lane == 8) ? q2 : q1;
        }
    }
    __syncthreads();

    // ---- phase 4 (cooperative): wave w owns output cols [256w, 256w+256)
    //      for ALL 4 rows; W_out slice + bias loaded once.
    {
        const int c4 = (w << 6) + lane;     // float4-col index; col0 = 4*c4
        const float4* wo = (const float4*)W_out;
        float4 wa[4], wb[4];
#pragma unroll
        for (int c = 0; c < 4; ++c) {
            wa[c] = wo[2 * (4 * c4 + c)];
            wb[c] = wo[2 * (4 * c4 + c) + 1];
        }
        float4 bias = ((const float4*)b_out)[c4];
#pragma unroll
        for (int r = 0; r < 4; ++r) {
            const float4* ev4 = (const float4*)evs[r];
            float4 lo = ev4[0], hi = ev4[1];
            f32x2 E01 = { lo.x, lo.y }, E23 = { lo.z, lo.w };
            f32x2 E45 = { hi.x, hi.y }, E67 = { hi.z, hi.w };
            float res[4];
#pragma unroll
            for (int c = 0; c < 4; ++c) {
                f32x2 a2 = E01 * (f32x2){ wa[c].x, wa[c].y } + E23 * (f32x2){ wa[c].z, wa[c].w }
                         + E45 * (f32x2){ wb[c].x, wb[c].y } + E67 * (f32x2){ wb[c].z, wb[c].w };
                res[c] = a2.x + a2.y;
            }
            float4 o;
            o.x = bias.x + res[0]; o.y = bias.y + res[1];
            o.z = bias.z + res[2]; o.w = bias.w + res[3];
            ((float4*)(out + (size_t)(block4 + r) * 1024))[c4] = o;
        }
    }
}

extern "C" void kernel_launch(void* const* d_in, const int* in_sizes, int n_in,
                              void* d_out, int out_size, void* d_ws, size_t ws_size,
                              hipStream_t stream) {
    const float* x     = (const float*)d_in[0];
    const float* W_in  = (const float*)d_in[1];
    const float* b_in  = (const float*)d_in[2];
    const float* qw    = (const float*)d_in[3];
    const float* W_out = (const float*)d_in[4];
    const float* b_out = (const float*)d_in[5];
    float* outp = (float*)d_out;

    const int B = in_sizes[0] / 1024;   // 8192 rows
    const int grid = B / 4;             // 4 rows (waves) per 256-thread block
    qasa_kernel<<<grid, 256, 0, stream>>>(x, W_in, b_in, qw, W_out, b_out, outp);
}

// Round 5
// 103.309 us; speedup vs baseline: 1.2171x; 1.0175x over previous
//
#include <hip/hip_runtime.h>
#include <math.h>

// QASA layer: out = circuit(x @ W_in.T + b_in, q_weights) @ W_out.T + b_out
// 8 qubits -> 256 complex amps. State idx = lane*4 + r: idx bits [7:2] =
// lane bits [5:0], bits [1:0] = reg. Wire i acts on idx bit 7-i.
//
// Round 5: 8 ROWS PER BLOCK, 2 rows per wave.
//  - Phase 1: two cooperative passes (rows 0-3, 4-7); each wave computes 2
//    q-rows x 4 batch-rows with ALL 24 float4 loads hoisted into locals
//    (deep VMEM pipelining; VGPR ~110 accepted, 16 waves/CU).
//  - Circuit: each wave runs TWO independent rows (ILP-2 chains). Row-B
//    per-wire factors are computed in lanes 16-27 of the same instruction
//    stream (free); product expansion uses rdlane<BASE+L>.
//  - Phase 4: wave w owns 256 cols for ALL 8 rows; W_out slice read once.
//  - W_in/W_out traffic per row halved vs round 4.
// Circuit algebra unchanged (CNOT ladders eliminated via F=I+S conjugation;
// layer 0 + embedding absorbed into product factors; f32x2 packed math).

typedef float f32x2 __attribute__((ext_vector_type(2)));

__device__ __forceinline__ int f2i(float v) { return __float_as_int(v); }
__device__ __forceinline__ float i2f(int v) { return __int_as_float(v); }

template <int CTRL>
__device__ __forceinline__ float dppf(float v) {
    return i2f(__builtin_amdgcn_update_dpp(0, f2i(v), CTRL, 0xF, 0xF, true));
}

// generalized xor-mask cross-lane: DPP where possible, ds_swizzle <32, shfl >=32
template <int ML>
__device__ __forceinline__ float gshm(float v) {
    static_assert(ML > 0 && ML < 64, "lane mask");
    if constexpr (ML == 1)      return dppf<0xB1>(v);        // quad_perm [1,0,3,2]
    else if constexpr (ML == 2) return dppf<0x4E>(v);        // quad_perm [2,3,0,1]
    else if constexpr (ML == 3) return dppf<0x1B>(v);        // quad_perm [3,2,1,0]
    else if constexpr (ML == 8) return dppf<0x128>(v);       // row_ror:8 == xor8 in 16
    else if constexpr (ML < 32) return i2f(__builtin_amdgcn_ds_swizzle(f2i(v), 0x1F | (ML << 10)));
    else                        return __shfl_xor(v, ML, 64);
}

template <int L>
__device__ __forceinline__ float rdlane(float v) {
    return i2f(__builtin_amdgcn_readlane(f2i(v), L));
}

// Generalized gate on packed state: RX(th1) about axis (lane-mask ML,
// reg-mask MR), then RZ(th2) with sign = parity(lane&ZL)^parity(r&ZR).
template <int ML, int MR, int ZL, int ZR>
__device__ __forceinline__ void ggate(f32x2& reA, f32x2& reB, f32x2& imA, f32x2& imB,
                                      float c1, float s1, float c2, float s2,
                                      int lane) {
    // ---- partner fetch: reg-swizzle by MR, then lane-xor by ML ----
    f32x2 sReA, sReB, sImA, sImB;
    if constexpr (MR == 0)      { sReA = reA;    sReB = reB;    sImA = imA;    sImB = imB; }
    else if constexpr (MR == 1) { sReA = reA.yx; sReB = reB.yx; sImA = imA.yx; sImB = imB.yx; }
    else if constexpr (MR == 2) { sReA = reB;    sReB = reA;    sImA = imB;    sImB = imA; }
    else                        { sReA = reB.yx; sReB = reA.yx; sImA = imB.yx; sImB = imA.yx; }
    f32x2 pReA, pReB, pImA, pImB;
    if constexpr (ML != 0) {
        pReA.x = gshm<ML>(sReA.x); pReA.y = gshm<ML>(sReA.y);
        pReB.x = gshm<ML>(sReB.x); pReB.y = gshm<ML>(sReB.y);
        pImA.x = gshm<ML>(sImA.x); pImA.y = gshm<ML>(sImA.y);
        pImB.x = gshm<ML>(sImB.x); pImB.y = gshm<ML>(sImB.y);
    } else { pReA = sReA; pReB = sReB; pImA = sImA; pImB = sImB; }
    // ---- RX ----
    f32x2 nReA = c1 * reA + s1 * pImA;
    f32x2 nReB = c1 * reB + s1 * pImB;
    f32x2 nImA = c1 * imA - s1 * pReA;
    f32x2 nImB = c1 * imB - s1 * pReB;
    // ---- RZ: ss_r = sigma(r) * base, base = parity(lane&ZL) ? s2 : -s2 ----
    float base;
    if constexpr (ZL == 0) base = -s2;
    else                   base = (__popc(lane & ZL) & 1) ? s2 : -s2;
    constexpr bool N1 = (ZR & 1) != 0;                       // sigma(1)
    constexpr bool N2 = ((ZR >> 1) & 1) != 0;                // sigma(2)
    constexpr bool N3 = (((ZR & 1) ^ ((ZR >> 1) & 1)) != 0); // sigma(3)
    f32x2 ssA = { base, N1 ? -base : base };
    f32x2 ssB = { N2 ? -base : base, N3 ? -base : base };
    f32x2 tA = c2 * nReA - ssA * nImA;
    f32x2 tB = c2 * nReB - ssB * nImB;
    imA = c2 * nImA + ssA * nReA;
    imB = c2 * nImB + ssB * nReB;
    reA = tA;
    reB = tB;
}

// Product expansion: state after layer 0 from per-wire factors held in
// lanes BASE+{0,1,2,3,8,9,10,11}.
template <int BASE>
__device__ __forceinline__ void expand_state(float ur2, float ui2, float vr2, float vi2,
                                             int lane,
                                             f32x2& reA, f32x2& reB, f32x2& imA, f32x2& imB) {
    float Pr, Pi;
    {   // wire 0 (lane bit 5), factor in lane BASE
        float fur = rdlane<BASE + 0>(ur2), fui = rdlane<BASE + 0>(ui2);
        float fvr = rdlane<BASE + 0>(vr2), fvi = rdlane<BASE + 0>(vi2);
        bool b = (lane >> 5) & 1;
        Pr = b ? fvr : fur;
        Pi = b ? fvi : fui;
    }
#define PMUL(W_, L_) { \
        float fur = rdlane<BASE + L_>(ur2), fui = rdlane<BASE + L_>(ui2); \
        float fvr = rdlane<BASE + L_>(vr2), fvi = rdlane<BASE + L_>(vi2); \
        bool b = (lane >> (5 - (W_))) & 1; \
        float fr = b ? fvr : fur, fi = b ? fvi : fui; \
        float tr = Pr * fr - Pi * fi; \
        Pi = Pr * fi + Pi * fr; \
        Pr = tr; }
    PMUL(1, 1) PMUL(2, 2) PMUL(3, 3) PMUL(4, 8) PMUL(5, 9)
#undef PMUL
    {   // wires 6 (reg bit1, lane BASE+10) and 7 (reg bit0, lane BASE+11)
        float u6r = rdlane<BASE + 10>(ur2), u6i = rdlane<BASE + 10>(ui2);
        float v6r = rdlane<BASE + 10>(vr2), v6i = rdlane<BASE + 10>(vi2);
        float u7r = rdlane<BASE + 11>(ur2), u7i = rdlane<BASE + 11>(ui2);
        float v7r = rdlane<BASE + 11>(vr2), v7i = rdlane<BASE + 11>(vi2);
        float rr[4], ii[4];
#pragma unroll
        for (int r = 0; r < 4; ++r) {
            float g6r_ = (r & 2) ? v6r : u6r, g6i_ = (r & 2) ? v6i : u6i;
            float g7r_ = (r & 1) ? v7r : u7r, g7i_ = (r & 1) ? v7i : u7i;
            float fr = g6r_ * g7r_ - g6i_ * g7i_;
            float fi = g6r_ * g7i_ + g6i_ * g7r_;
            rr[r] = Pr * fr - Pi * fi;
            ii[r] = Pr * fi + Pi * fr;
        }
        reA = (f32x2){ rr[0], rr[1] };  reB = (f32x2){ rr[2], rr[3] };
        imA = (f32x2){ ii[0], ii[1] };  imB = (f32x2){ ii[2], ii[3] };
    }
}

__global__ void __launch_bounds__(256, 4) qasa_kernel(
    const float* __restrict__ x, const float* __restrict__ W_in,
    const float* __restrict__ b_in, const float* __restrict__ qw,
    const float* __restrict__ W_out, const float* __restrict__ b_out,
    float* __restrict__ out)
{
    const int tid = threadIdx.x;
    const int lane = tid & 63;
    const int w = tid >> 6;                       // wave id in block
    const int block8 = blockIdx.x * 8;

    __shared__ float ang[64];                     // [q][8 rows]
    __shared__ float evs[8][8] __attribute__((aligned(16)));  // [row][ev]

    // per-wave layer trig, lane-indexed in VGPRs (qw has exactly 64 entries)
    float vc, vs;
    __sincosf(0.5f * qw[lane], &vs, &vc);

    const int b0 = lane & 1, b1 = (lane >> 1) & 1, b3 = (lane >> 3) & 1;

    // ---- phase 1 (cooperative, 2 passes): wave w computes angles for
    //      q = 2w, 2w+1 over rows 4g..4g+3; all 24 loads hoisted.
#pragma unroll
    for (int g = 0; g < 2; ++g) {
        const float4* w4 = (const float4*)W_in;
        const float4* xr0 = (const float4*)(x + (size_t)(block8 + 4 * g) * 1024);
        float4 wv0[4], wv1[4], xv[4][4];
#pragma unroll
        for (int k = 0; k < 4; ++k) {
            wv0[k] = w4[(2 * w) * 256 + lane + 64 * k];
            wv1[k] = w4[(2 * w + 1) * 256 + lane + 64 * k];
        }
#pragma unroll
        for (int r = 0; r < 4; ++r)
#pragma unroll
            for (int k = 0; k < 4; ++k)
                xv[r][k] = xr0[r * 256 + lane + 64 * k];

        float acc[8] = {0.f, 0.f, 0.f, 0.f, 0.f, 0.f, 0.f, 0.f};  // [qp*4 + r]
#pragma unroll
        for (int k = 0; k < 4; ++k)
#pragma unroll
            for (int r = 0; r < 4; ++r) {
                float4 xvv = xv[r][k];
                acc[r]     += xvv.x * wv0[k].x + xvv.y * wv0[k].y + xvv.z * wv0[k].z + xvv.w * wv0[k].w;
                acc[4 + r] += xvv.x * wv1[k].x + xvv.y * wv1[k].y + xvv.z * wv1[k].z + xvv.w * wv1[k].w;
            }
        // partial-reduce each acc over lane bits {0,1,3} (DPP only)
#pragma unroll
        for (int j = 0; j < 8; ++j) {
            acc[j] += dppf<0xB1>(acc[j]);
            acc[j] += dppf<0x4E>(acc[j]);
            acc[j] += dppf<0x128>(acc[j]);
        }
        // transpose: lane picks acc[j], j = b0 | b1<<1 | b3<<2
        float t01 = b0 ? acc[1] : acc[0];
        float t23 = b0 ? acc[3] : acc[2];
        float t45 = b0 ? acc[5] : acc[4];
        float t67 = b0 ? acc[7] : acc[6];
        float ta = b1 ? t23 : t01;
        float tb = b1 ? t67 : t45;
        float S = b3 ? tb : ta;
        // finish: sum over lane bits {2,4,5}
        S += gshm<4>(S); S += gshm<16>(S); S += gshm<32>(S);
        // writer lanes {0,1,2,3,8,9,10,11}: q = 2w + b3, r = lane&3
        if ((lane & 52) == 0)
            ang[(2 * w + ((lane >> 3) & 1)) * 8 + 4 * g + (lane & 3)] = S;
    }
    __syncthreads();

    // ---- phase 2a: per-wire factors for BOTH rows in one stream ----
    // lanes 0-11: row w (group A); lanes 16-27: row w+4 (group B)
    const int qofl = b0 | (b1 << 1) | (b3 << 2);  // qubit index held by this lane
    const int rsel = w + ((lane >> 2) & 4);       // row for this lane's group
    float A = ang[qofl * 8 + rsel] + b_in[qofl];
    float ca, sa;
    __sincosf(0.5f * A, &sa, &ca);
    // embedding part: u = (ca^2, -ca*sa), v = (sa^2, -ca*sa)
    float ur = ca * ca, ui = -ca * sa, vr = sa * sa, vi = ui;
    const int a1 = 4 * qofl, a2 = 4 * (qofl + 8);
    float cx = i2f(__builtin_amdgcn_ds_bpermute(a1, f2i(vc)));
    float sx = i2f(__builtin_amdgcn_ds_bpermute(a1, f2i(vs)));
    float cz = i2f(__builtin_amdgcn_ds_bpermute(a2, f2i(vc)));
    float sz = i2f(__builtin_amdgcn_ds_bpermute(a2, f2i(vs)));
    // RX(qx): u' = cx*u - i sx*v ; v' = cx*v - i sx*u
    float ur1 = cx * ur + sx * vi, ui1 = cx * ui - sx * vr;
    float vr1 = cx * vr + sx * ui, vi1 = cx * vi - sx * ur;
    // RZ(qz): u'' = (cz - i sz) u' ; v'' = (cz + i sz) v'
    float ur2 = cz * ur1 + sz * ui1, ui2 = cz * ui1 - sz * ur1;
    float vr2 = cz * vr1 - sz * vi1, vi2 = cz * vi1 + sz * vr1;

    // ---- phase 2b-init: product expansion for both rows ----
    f32x2 reA0, reB0, imA0, imB0;   // row w
    f32x2 reA1, reB1, imA1, imB1;   // row w+4
    expand_state<0>(ur2, ui2, vr2, vi2, lane, reA0, reB0, imA0, imB0);
    expand_state<16>(ur2, ui2, vr2, vi2, lane, reA1, reB1, imA1, imB1);

    // ---- phase 2b: layers 1-3 on both rows (independent ILP-2 chains) ----
    // qw[l][0][i] -> lane 16l+i (RX), qw[l][1][i] -> lane 16l+8+i (RZ)
#define GG(Lx, W_, ML_, MR_, ZL_, ZR_) { \
    float c1 = rdlane<16 * (Lx) + (W_)>(vc), s1 = rdlane<16 * (Lx) + (W_)>(vs); \
    float c2 = rdlane<16 * (Lx) + 8 + (W_)>(vc), s2 = rdlane<16 * (Lx) + 8 + (W_)>(vs); \
    ggate<ML_, MR_, ZL_, ZR_>(reA0, reB0, imA0, imB0, c1, s1, c2, s2, lane); \
    ggate<ML_, MR_, ZL_, ZR_>(reA1, reB1, imA1, imB1, c1, s1, c2, s2, lane); }

    // layer 2 (a=1): axis F e_k = {k,k-1}; RZ rows of F^-1 = {k..7}
    GG(1,0, 48,0, 32,0)  GG(1,1, 24,0, 48,0)  GG(1,2, 12,0, 56,0) GG(1,3, 6,0, 60,0)
    GG(1,4, 3,0, 62,0)   GG(1,5, 1,2, 63,0)   GG(1,6, 0,3, 63,2)  GG(1,7, 0,1, 63,3)
    // layer 3 (a=2): axis {k,k-2}; RZ rows of F^-2 = {k,k+2,k+4,k+6}
    GG(2,0, 40,0, 32,0)  GG(2,1, 20,0, 16,0)  GG(2,2, 10,0, 40,0) GG(2,3, 5,0, 20,0)
    GG(2,4, 2,2, 42,0)   GG(2,5, 1,1, 21,0)   GG(2,6, 0,2, 42,2)  GG(2,7, 0,1, 21,1)
    // layer 4 (a=3): axis {k,k-1,k-2,k-3}; RZ rows of F^-3 = {k,k+1,k+4,k+5}
    GG(3,0, 60,0, 32,0)  GG(3,1, 30,0, 48,0)  GG(3,2, 15,0, 24,0) GG(3,3, 7,2, 12,0)
    GG(3,4, 3,3, 38,0)   GG(3,5, 1,3, 51,0)   GG(3,6, 0,3, 25,2)  GG(3,7, 0,1, 12,3)
#undef GG

    // ---- phase 3: expvals for both rows (F^-4-absorbed masks) ----
#define BUTTERFLY(reA, reB, imA, imB, vq0, vq1, vq2) \
    float p0 = reA.x * reA.x + imA.x * imA.x; \
    float p1 = reA.y * reA.y + imA.y * imA.y; \
    float p2 = reB.x * reB.x + imB.x * imB.x; \
    float p3 = reB.y * reB.y + imB.y * imB.y; \
    float vq0 = (p0 + p1) + (p2 + p3); \
    float vq2 = (p0 + p1) - (p2 + p3); \
    float vq1 = (p0 + p2) - (p1 + p3); \
    { float u = dppf<0xB1>(vq0);  vq0 = (lane & 1)  ? (u - vq0) : (vq0 + u); } \
    { float u = dppf<0x4E>(vq0);  vq0 = (lane & 2)  ? (u - vq0) : (vq0 + u); } \
    { float u = dppf<0x128>(vq0); vq0 = (lane & 8)  ? (u - vq0) : (vq0 + u); } \
    { float u = gshm<4>(vq0);     vq0 = (lane & 4)  ? (u - vq0) : (vq0 + u); } \
    { float u = gshm<16>(vq0);    vq0 = (lane & 16) ? (u - vq0) : (vq0 + u); } \
    { float u = gshm<32>(vq0);    vq0 = (lane & 32) ? (u - vq0) : (vq0 + u); } \
    vq2 += dppf<0xB1>(vq2); \
    vq2 += dppf<0x4E>(vq2); \
    { float u = dppf<0x128>(vq2); vq2 = (lane & 8) ? (u - vq2) : (vq2 + u); } \
    vq2 += gshm<4>(vq2); vq2 += gshm<16>(vq2); vq2 += gshm<32>(vq2); \
    vq1 += dppf<0xB1>(vq1); \
    vq1 += dppf<0x4E>(vq1); \
    vq1 += dppf<0x128>(vq1); \
    { float u = gshm<4>(vq1); vq1 = (lane & 4) ? (u - vq1) : (vq1 + u); } \
    vq1 += gshm<16>(vq1); vq1 += gshm<32>(vq1);

    float v0, v1, q1A, q1B, q2A, q2B;
    { BUTTERFLY(reA0, reB0, imA0, imB0, vv, w1, w2) v0 = vv; q1A = w1; q2A = w2; }
    { BUTTERFLY(reA1, reB1, imA1, imB1, vv, w1, w2) v1 = vv; q1B = w1; q2B = w2; }
#undef BUTTERFLY

    // write EVs to LDS directly from their holder lanes (both rows)
    {
        const unsigned long long wrmask = 0x0000000500030110ULL; // lanes 4,8,16,17,32,34
        if ((wrmask >> lane) & 1) {
            int k = 6 - __ffs(lane);        // 32->0,16->1,8->2,4->3,34->4,17->5
            evs[w][k] = v0;
            evs[w + 4][k] = v1;
        }
        if (lane == 8) { evs[w][6] = q2A; evs[w + 4][6] = q2B; }
        if (lane == 4) { evs[w][7] = q1A; evs[w + 4][7] = q1B; }
    }
    __syncthreads();

    // ---- phase 4 (cooperative): wave w owns cols [256w, 256w+256) for
    //      ALL 8 rows; W_out slice + bias loaded once.
    {
        const int c4 = (w << 6) + lane;     // float4-col index; col0 = 4*c4
        const float4* wo = (const float4*)W_out;
        float4 wa[4], wb[4];
#pragma unroll
        for (int c = 0; c < 4; ++c) {
            wa[c] = wo[2 * (4 * c4 + c)];
            wb[c] = wo[2 * (4 * c4 + c) + 1];
        }
        float4 bias = ((const float4*)b_out)[c4];
#pragma unroll
        for (int r = 0; r < 8; ++r) {
            const float4* ev4 = (const float4*)evs[r];
            float4 lo = ev4[0], hi = ev4[1];
            f32x2 E01 = { lo.x, lo.y }, E23 = { lo.z, lo.w };
            f32x2 E45 = { hi.x, hi.y }, E67 = { hi.z, hi.w };
            float res[4];
#pragma unroll
            for (int c = 0; c < 4; ++c) {
                f32x2 a2 = E01 * (f32x2){ wa[c].x, wa[c].y } + E23 * (f32x2){ wa[c].z, wa[c].w }
                         + E45 * (f32x2){ wb[c].x, wb[c].y } + E67 * (f32x2){ wb[c].z, wb[c].w };
                res[c] = a2.x + a2.y;
            }
            float4 o;
            o.x = bias.x + res[0]; o.y = bias.y + res[1];
            o.z = bias.z + res[2]; o.w = bias.w + res[3];
            ((float4*)(out + (size_t)(block8 + r) * 1024))[c4] = o;
        }
    }
}

extern "C" void kernel_launch(void* const* d_in, const int* in_sizes, int n_in,
                              void* d_out, int out_size, void* d_ws, size_t ws_size,
                              hipStream_t stream) {
    const float* x     = (const float*)d_in[0];
    const float* W_in  = (const float*)d_in[1];
    const float* b_in  = (const float*)d_in[2];
    const float* qw    = (const float*)d_in[3];
    const float* W_out = (const float*)d_in[4];
    const float* b_out = (const float*)d_in[5];
    float* outp = (float*)d_out;

    const int B = in_sizes[0] / 1024;   // 8192 rows
    const int grid = B / 8;             // 8 rows per 256-thread block
    qasa_kernel<<<grid, 256, 0, stream>>>(x, W_in, b_in, qw, W_out, b_out, outp);
}